// Round 1
// baseline (17988.704 us; speedup 1.0000x reference)
//
#include <hip/hip_runtime.h>

#define BSZ 8192
#define LH 20
#define NFD 172
#define DD 860        // D = 172*4 + 172
#define DHH 430       // D / 2 heads
#define KP 864        // D padded to mult of 32
#define NQKV 2580     // 3*D
#define LDQ 2688      // 3*D padded to mult of 128

typedef float f32x4 __attribute__((ext_vector_type(4)));
typedef __bf16 v8bf16 __attribute__((ext_vector_type(8)));

typedef __attribute__((address_space(3))) void lds_void;
typedef const __attribute__((address_space(1))) void global_void;

static __device__ __forceinline__ unsigned short f2b(float f) {
    union { float f; unsigned u; } U; U.f = f;
    unsigned r = (U.u + 0x7fffu + ((U.u >> 16) & 1u)) >> 16;
    return (unsigned short)r;
}
static __device__ __forceinline__ float b2f(unsigned short x) {
    union { unsigned u; float f; } U; U.u = ((unsigned)x) << 16; return U.f;
}
static __device__ __forceinline__ void async16(const void* g, void* l) {
    __builtin_amdgcn_global_load_lds((global_void*)g, (lds_void*)l, 16, 0, 0);
}

// ---------------------------------------------------------------------------
// Weight convert + zero-pad: src fp32 (N,K) -> dst bf16 (Np,Kp)
// ---------------------------------------------------------------------------
__global__ __launch_bounds__(256) void pad_convert(
    const float* __restrict__ src, unsigned short* __restrict__ dst,
    int N, int K, int Np, int Kp)
{
    int total = Np * Kp;
    for (int i = blockIdx.x * blockDim.x + threadIdx.x; i < total;
         i += gridDim.x * blockDim.x) {
        int n = i / Kp, k = i - (i / Kp) * Kp;
        float v = (n < N && k < K) ? src[(size_t)n * K + k] : 0.f;
        dst[i] = f2b(v);
    }
}

// ---------------------------------------------------------------------------
// Build `full` (chunk rows x KP, bf16), last-event-feat into xbuf cols 172..,
// prev_ts output. One block per (b,j) row.
// ---------------------------------------------------------------------------
__global__ __launch_bounds__(256) void build_kernel(
    const int* __restrict__ nids, const int* __restrict__ hist_nids,
    const int* __restrict__ aids, const int* __restrict__ eids,
    const float* __restrict__ ts, const int* __restrict__ dirs,
    const float* __restrict__ node_emb, const float* __restrict__ edge_emb,
    const float* __restrict__ anony_emb, const float* __restrict__ time_w,
    const float* __restrict__ time_b,
    unsigned short* __restrict__ full, unsigned short* __restrict__ xbuf,
    float* __restrict__ prev_ts, int c0)
{
    int idx = blockIdx.x;
    int b = c0 + idx / LH;
    int j = idx - (idx / LH) * LH;
    int nid = nids[b];
    int hn  = hist_nids[b * LH + j];
    int dir = dirs[b * LH + j];
    int src = dir ? nid : hn;
    int dst = dir ? hn : nid;
    int aid = aids[b * LH + j];
    int eid = eids[b * LH + j];
    float tlast = ts[b * LH + (LH - 1)];
    float dt = tlast - ts[b * LH + j];
    bool last = (j == LH - 1);
    unsigned short* frow = full + (size_t)idx * KP;

    for (int c = threadIdx.x; c < KP; c += blockDim.x) {
        float v;
        if (c < NFD)            v = node_emb[(size_t)src * NFD + c];
        else if (c < 2 * NFD)   v = node_emb[(size_t)dst * NFD + (c - NFD)];
        else if (c < 3 * NFD)   v = anony_emb[(size_t)aid * NFD + (c - 2 * NFD)];
        else if (c < 4 * NFD)   v = edge_emb[(size_t)eid * NFD + (c - 3 * NFD)];
        else if (c < DD) { int tf = c - 4 * NFD; v = cosf(dt * time_w[tf] + time_b[tf]); }
        else                    v = 0.f;
        unsigned short bv = f2b(v);
        if (last) {
            if (c < 4 * NFD) {
                // last_event_feat -> x cols [172, 860); zero the full row entry
                xbuf[(size_t)b * KP + NFD + c] = bv;
                frow[c] = 0;
            } else {
                frow[c] = bv;
                if (c < 4 * NFD + 4) xbuf[(size_t)b * KP + NFD + c] = 0; // x cols 860..863 = 0
            }
        } else {
            frow[c] = bv;
        }
    }
    if (last && threadIdx.x == 0) prev_ts[b] = tlast;
}

// ---------------------------------------------------------------------------
// bf16 MFMA GEMM: C[M,N] = A[M,Kp] @ B[N,Kp]^T (+bias, opt relu)
// m97 structure: 128x128 tile, BK=32, 4 waves (2x2 of 64x64), global_load_lds.
// outF: fp32 store for col<nF (stride ldF). outB: bf16 store, val for col<N,
// zero for N<=col<nB (stride ldB).
// ---------------------------------------------------------------------------
__global__ __launch_bounds__(256) void gemm_bt(
    const unsigned short* __restrict__ A, const unsigned short* __restrict__ B,
    const float* __restrict__ bias, int Kp, int N,
    float* __restrict__ outF, int ldF, int nF,
    unsigned short* __restrict__ outB, int ldB, int nB, int relu)
{
    __shared__ __align__(16) unsigned short As[128 * 32];
    __shared__ __align__(16) unsigned short Bs[128 * 32];
    int tid = threadIdx.x;
    int w = tid >> 6, lane = tid & 63;
    int r = lane & 15, q = lane >> 4;
    int m0 = blockIdx.x * 128;
    int n0 = blockIdx.y * 128;
    int wm = (w >> 1) * 64, wn = (w & 1) * 64;
    f32x4 acc[4][4] = {};
    int ktiles = Kp >> 5;

    for (int kt = 0; kt < ktiles; ++kt) {
        int k0 = kt * 32;
        for (int iss = 0; iss < 2; ++iss) {
            int chunk = iss * 256 + w * 64 + lane;       // 0..511
            int mm = chunk >> 2, kc = chunk & 3;
            const unsigned short* ga = A + (size_t)(m0 + mm) * Kp + k0 + kc * 8;
            async16(ga, &As[(size_t)(iss * 256 + w * 64) * 8]);
            const unsigned short* gb = B + (size_t)(n0 + mm) * Kp + k0 + kc * 8;
            async16(gb, &Bs[(size_t)(iss * 256 + w * 64) * 8]);
        }
        __syncthreads();
        v8bf16 af[4], bfr[4];
        for (int im = 0; im < 4; ++im)
            af[im] = *(const v8bf16*)&As[(wm + im * 16 + r) * 32 + q * 8];
        for (int in = 0; in < 4; ++in)
            bfr[in] = *(const v8bf16*)&Bs[(wn + in * 16 + r) * 32 + q * 8];
        for (int im = 0; im < 4; ++im)
            for (int in = 0; in < 4; ++in)
                acc[im][in] = __builtin_amdgcn_mfma_f32_16x16x32_bf16(
                    af[im], bfr[in], acc[im][in], 0, 0, 0);
        __syncthreads();
    }

    for (int im = 0; im < 4; ++im) {
        int rowb = m0 + wm + im * 16 + q * 4;
        for (int in = 0; in < 4; ++in) {
            int col = n0 + wn + in * 16 + r;
            float bv = (col < N) ? bias[col] : 0.f;
            for (int reg = 0; reg < 4; ++reg) {
                float v = acc[im][in][reg];
                if (col < N) { v += bv; if (relu) v = fmaxf(v, 0.f); }
                else v = 0.f;
                int rr = rowb + reg;
                if (outF && col < nF) outF[(size_t)rr * ldF + col] = v;
                if (outB && col < nB) outB[(size_t)rr * ldB + col] = f2b(v);
            }
        }
    }
}

// ---------------------------------------------------------------------------
// Attention per b: S=QK^T via MFMA, softmax w/ mask, pbar = mean_i P,
// mean_ctx[d] = sum_j pbar[j] * V[j,d]  (mean over queries folded into pbar).
// ---------------------------------------------------------------------------
static __device__ __forceinline__ v8bf16 load_frag(
    const unsigned short* row, int colbase, int d0)
{
    union { unsigned u[4]; v8bf16 v; unsigned short s[8]; } U;
    if (d0 + 8 <= DHH) {
        const unsigned* p = (const unsigned*)(row + colbase + d0);
        U.u[0] = p[0]; U.u[1] = p[1]; U.u[2] = p[2]; U.u[3] = p[3];
    } else {
        for (int t = 0; t < 8; ++t)
            U.s[t] = (d0 + t < DHH) ? row[colbase + d0 + t] : (unsigned short)0;
    }
    return U.v;
}

__global__ __launch_bounds__(256) void attn_kernel(
    const unsigned short* __restrict__ qkv,  // chunk rows x LDQ
    const int* __restrict__ hist_nids,
    unsigned short* __restrict__ mean_ctx,   // BSZ x KP bf16
    int c0)
{
    __shared__ float Sp[2][2][LH][LH];
    __shared__ float P[2][LH][LH];
    __shared__ float pbar[2][LH];
    __shared__ int maskv[LH];
    int b = c0 + blockIdx.x;
    int tid = threadIdx.x;
    int lane = tid & 63, w = tid >> 6;
    int r = lane & 15, q = lane >> 4;
    if (tid < LH) maskv[tid] = (hist_nids[b * LH + tid] == 0 && tid != LH - 1) ? 1 : 0;

    const unsigned short* base = qkv + (size_t)blockIdx.x * LH * LDQ;
    int h = w & 1, kh = w >> 1;
    int qoff = h * DHH;
    int koff = DD + h * DHH;
    f32x4 sacc[2][2] = {};
    for (int step = 0; step < 7; ++step) {
        int k0 = kh * 224 + step * 32;
        v8bf16 qf[2], kf[2];
        for (int im = 0; im < 2; ++im) {
            int mm = im * 16 + r; if (mm >= LH) mm = LH - 1;
            const unsigned short* rp = base + (size_t)mm * LDQ;
            qf[im] = load_frag(rp, qoff, k0 + q * 8);
            kf[im] = load_frag(rp, koff, k0 + q * 8);
        }
        for (int im = 0; im < 2; ++im)
            for (int in = 0; in < 2; ++in)
                sacc[im][in] = __builtin_amdgcn_mfma_f32_16x16x32_bf16(
                    qf[im], kf[in], sacc[im][in], 0, 0, 0);
    }
    for (int im = 0; im < 2; ++im)
        for (int in = 0; in < 2; ++in)
            for (int reg = 0; reg < 4; ++reg) {
                int i = im * 16 + q * 4 + reg, jj = in * 16 + r;
                if (i < LH && jj < LH) Sp[h][kh][i][jj] = sacc[im][in][reg];
            }
    __syncthreads();

    if (tid < 2 * LH) {
        int hh = tid / LH, i = tid - (tid / LH) * LH;
        const float scale = 0.0482242822f;  // 1/sqrt(430)
        float s[LH], mx = -1e30f;
        for (int jj = 0; jj < LH; ++jj) {
            float v = (Sp[hh][0][i][jj] + Sp[hh][1][i][jj]) * scale;
            if (maskv[jj]) v = -1e30f;
            s[jj] = v; mx = fmaxf(mx, v);
        }
        float sum = 0.f;
        for (int jj = 0; jj < LH; ++jj) { float e = expf(s[jj] - mx); s[jj] = e; sum += e; }
        float inv = 1.f / sum;
        for (int jj = 0; jj < LH; ++jj) P[hh][i][jj] = s[jj] * inv;
    }
    __syncthreads();
    if (tid < 2 * LH) {
        int hh = tid / LH, jj = tid - (tid / LH) * LH;
        float a = 0.f;
        for (int i = 0; i < LH; ++i) a += P[hh][i][jj];
        pbar[hh][jj] = a * (1.f / LH);
    }
    __syncthreads();

    for (int d = tid; d < KP; d += 256) {
        float a = 0.f;
        if (d < DD) {
            int hh = d < DHH ? 0 : 1;
            int dd = d - hh * DHH;
            int voff = 2 * DD + hh * DHH + dd;
            for (int jj = 0; jj < LH; ++jj)
                a += pbar[hh][jj] * b2f(base[(size_t)jj * LDQ + voff]);
        }
        mean_ctx[(size_t)b * KP + d] = f2b(a);
    }
}

// ---------------------------------------------------------------------------
extern "C" void kernel_launch(void* const* d_in, const int* in_sizes, int n_in,
                              void* d_out, int out_size, void* d_ws, size_t ws_size,
                              hipStream_t stream)
{
    const int*   nids      = (const int*)d_in[0];
    const int*   hist_nids = (const int*)d_in[1];
    const int*   aids      = (const int*)d_in[2];
    const int*   eids      = (const int*)d_in[3];
    const float* hist_ts   = (const float*)d_in[4];
    const int*   dirs      = (const int*)d_in[5];
    const float* node_emb  = (const float*)d_in[6];
    const float* edge_emb  = (const float*)d_in[7];
    const float* anony_emb = (const float*)d_in[8];
    const float* time_w    = (const float*)d_in[9];
    const float* time_b    = (const float*)d_in[10];
    const float* in_proj_w = (const float*)d_in[11];
    const float* in_proj_b = (const float*)d_in[12];
    const float* out_proj_w= (const float*)d_in[13];
    const float* out_proj_b= (const float*)d_in[14];
    const float* outfn_w   = (const float*)d_in[15];
    const float* outfn_b   = (const float*)d_in[16];
    const float* fc1_w     = (const float*)d_in[17];
    const float* fc1_b     = (const float*)d_in[18];
    const float* fc2_w     = (const float*)d_in[19];
    const float* fc2_b     = (const float*)d_in[20];

    float* out_left  = (float*)d_out;
    float* out_right = out_left + (size_t)BSZ * NFD;
    float* out_ts    = out_right + (size_t)BSZ * NFD;

    char* p = (char*)d_ws;
    auto alloc = [&](size_t bytes) -> char* {
        char* r = p; p += (bytes + 255) & ~(size_t)255; return r;
    };
    unsigned short* Wqkv = (unsigned short*)alloc((size_t)LDQ * KP * 2);
    unsigned short* Wop  = (unsigned short*)alloc((size_t)896 * KP * 2);
    unsigned short* Wofn = (unsigned short*)alloc((size_t)256 * 896 * 2);
    unsigned short* Wfc1 = (unsigned short*)alloc((size_t)256 * KP * 2);
    unsigned short* Wfc2 = (unsigned short*)alloc((size_t)256 * 192 * 2);
    unsigned short* meanctx = (unsigned short*)alloc((size_t)BSZ * KP * 2);
    unsigned short* xbuf    = (unsigned short*)alloc((size_t)BSZ * KP * 2);
    unsigned short* tmp1    = (unsigned short*)alloc((size_t)BSZ * 896 * 2);
    unsigned short* hbuf    = (unsigned short*)alloc((size_t)BSZ * 192 * 2);
    size_t fixed = (size_t)(p - (char*)d_ws);

    int CB = 1024;  // chunk of batch; qkv chunk ~110MB stays L3-resident
    while (CB > 128) {
        size_t need = fixed + (size_t)CB * LH * KP * 2 + (size_t)CB * LH * LDQ * 2 + 4096;
        if (need <= ws_size) break;
        CB >>= 1;
    }
    unsigned short* fullc = (unsigned short*)alloc((size_t)CB * LH * KP * 2);
    unsigned short* qkvc  = (unsigned short*)alloc((size_t)CB * LH * LDQ * 2);

    auto conv = [&](const float* s, unsigned short* d, int N_, int K_, int Np_, int Kp_) {
        int total = Np_ * Kp_;
        int blocks = (total + 255) / 256; if (blocks > 4096) blocks = 4096;
        pad_convert<<<dim3(blocks), dim3(256), 0, stream>>>(s, d, N_, K_, Np_, Kp_);
    };
    conv(in_proj_w,  Wqkv, NQKV, DD, LDQ, KP);
    conv(out_proj_w, Wop,  DD,   DD, 896, KP);
    conv(outfn_w,    Wofn, NFD,  DD, 256, 896);
    conv(fc1_w,      Wfc1, NFD,  DD, 256, KP);
    conv(fc2_w,      Wfc2, NFD,  NFD, 256, 192);

    for (int c0 = 0; c0 < BSZ; c0 += CB) {
        build_kernel<<<dim3(CB * LH), dim3(256), 0, stream>>>(
            nids, hist_nids, aids, eids, hist_ts, dirs,
            node_emb, edge_emb, anony_emb, time_w, time_b,
            fullc, xbuf, out_ts, c0);
        gemm_bt<<<dim3(CB * LH / 128, LDQ / 128), dim3(256), 0, stream>>>(
            fullc, Wqkv, in_proj_b, KP, NQKV,
            (float*)nullptr, 0, 0, qkvc, LDQ, LDQ, 0);
        attn_kernel<<<dim3(CB), dim3(256), 0, stream>>>(qkvc, hist_nids, meanctx, c0);
    }
    // E1: tmp1 = relu(mean_ctx @ Wop^T + b)   (mean folded through out_proj)
    gemm_bt<<<dim3(BSZ / 128, 7), dim3(256), 0, stream>>>(
        meanctx, Wop, out_proj_b, KP, DD,
        (float*)nullptr, 0, 0, tmp1, 896, 896, 1);
    // E2: h_prev_left = tmp1 @ Wofn^T + b  -> d_out (fp32) and x cols 0..171 (bf16)
    gemm_bt<<<dim3(BSZ / 128, 2), dim3(256), 0, stream>>>(
        tmp1, Wofn, outfn_b, 896, NFD,
        out_left, NFD, NFD, xbuf, KP, NFD, 0);
    // E3: h = relu(x @ Wfc1^T + b) -> bf16 (zero-padded to 192)
    gemm_bt<<<dim3(BSZ / 128, 2), dim3(256), 0, stream>>>(
        xbuf, Wfc1, fc1_b, KP, NFD,
        (float*)nullptr, 0, 0, hbuf, 192, 192, 1);
    // E4: h_prev_right = h @ Wfc2^T + b -> d_out
    gemm_bt<<<dim3(BSZ / 128, 2), dim3(256), 0, stream>>>(
        hbuf, Wfc2, fc2_b, 192, NFD,
        out_right, NFD, NFD, (unsigned short*)nullptr, 0, 0, 0);
}

// Round 2
// 2293.302 us; speedup vs baseline: 7.8440x; 7.8440x over previous
//
#include <hip/hip_runtime.h>

#define BSZ 8192
#define LH 20
#define NFD 172
#define DD 860        // D = 172*4 + 172
#define DHH 430       // D / 2 heads
#define KP 864        // D padded to mult of 32
#define NQKV 2580     // 3*D
#define LDQ 2688      // 3*D padded to mult of 128

typedef float f32x4 __attribute__((ext_vector_type(4)));
typedef __bf16 v8bf16 __attribute__((ext_vector_type(8)));

typedef __attribute__((address_space(3))) void lds_void;
typedef const __attribute__((address_space(1))) void global_void;

static __device__ __forceinline__ unsigned short f2b(float f) {
    union { float f; unsigned u; } U; U.f = f;
    unsigned r = (U.u + 0x7fffu + ((U.u >> 16) & 1u)) >> 16;
    return (unsigned short)r;
}
static __device__ __forceinline__ float b2f(unsigned short x) {
    union { unsigned u; float f; } U; U.u = ((unsigned)x) << 16; return U.f;
}
static __device__ __forceinline__ void async16(const void* g, void* l) {
    __builtin_amdgcn_global_load_lds((global_void*)g, (lds_void*)l, 16, 0, 0);
}

// ---------------------------------------------------------------------------
// Weight convert + zero-pad: src fp32 (N,K) -> dst bf16 (Np,Kp)
// ---------------------------------------------------------------------------
__global__ __launch_bounds__(256) void pad_convert(
    const float* __restrict__ src, unsigned short* __restrict__ dst,
    int N, int K, int Np, int Kp)
{
    int total = Np * Kp;
    for (int i = blockIdx.x * blockDim.x + threadIdx.x; i < total;
         i += gridDim.x * blockDim.x) {
        int n = i / Kp, k = i - (i / Kp) * Kp;
        float v = (n < N && k < K) ? src[(size_t)n * K + k] : 0.f;
        dst[i] = f2b(v);
    }
}

// ---------------------------------------------------------------------------
// Build `full` (chunk rows x KP, bf16), last-event-feat into xbuf cols 172..,
// prev_ts output. One block per (b,j) row.
// ---------------------------------------------------------------------------
__global__ __launch_bounds__(256) void build_kernel(
    const int* __restrict__ nids, const int* __restrict__ hist_nids,
    const int* __restrict__ aids, const int* __restrict__ eids,
    const float* __restrict__ ts, const int* __restrict__ dirs,
    const float* __restrict__ node_emb, const float* __restrict__ edge_emb,
    const float* __restrict__ anony_emb, const float* __restrict__ time_w,
    const float* __restrict__ time_b,
    unsigned short* __restrict__ full, unsigned short* __restrict__ xbuf,
    float* __restrict__ prev_ts, int c0)
{
    int idx = blockIdx.x;
    int b = c0 + idx / LH;
    int j = idx - (idx / LH) * LH;
    int nid = nids[b];
    int hn  = hist_nids[b * LH + j];
    int dir = dirs[b * LH + j];
    int src = dir ? nid : hn;
    int dst = dir ? hn : nid;
    int aid = aids[b * LH + j];
    int eid = eids[b * LH + j];
    float tlast = ts[b * LH + (LH - 1)];
    float dt = tlast - ts[b * LH + j];
    bool last = (j == LH - 1);
    unsigned short* frow = full + (size_t)idx * KP;

    for (int c = threadIdx.x; c < KP; c += blockDim.x) {
        float v;
        if (c < NFD)            v = node_emb[(size_t)src * NFD + c];
        else if (c < 2 * NFD)   v = node_emb[(size_t)dst * NFD + (c - NFD)];
        else if (c < 3 * NFD)   v = anony_emb[(size_t)aid * NFD + (c - 2 * NFD)];
        else if (c < 4 * NFD)   v = edge_emb[(size_t)eid * NFD + (c - 3 * NFD)];
        else if (c < DD) { int tf = c - 4 * NFD; v = cosf(dt * time_w[tf] + time_b[tf]); }
        else                    v = 0.f;
        unsigned short bv = f2b(v);
        if (last) {
            if (c < 4 * NFD) {
                // last_event_feat -> x cols [172, 860); zero the full row entry
                xbuf[(size_t)b * KP + NFD + c] = bv;
                frow[c] = 0;
            } else {
                frow[c] = bv;
                if (c < 4 * NFD + 4) xbuf[(size_t)b * KP + NFD + c] = 0; // x cols 860..863 = 0
            }
        } else {
            frow[c] = bv;
        }
    }
    if (last && threadIdx.x == 0) prev_ts[b] = tlast;
}

// ---------------------------------------------------------------------------
// bf16 MFMA GEMM: C[M,N] = A[M,Kp] @ B[N,Kp]^T (+bias, opt relu)
// m97 structure: 128x128 tile, BK=32, 4 waves (2x2 of 64x64), global_load_lds.
// FULL UNROLL on every loop touching acc[][]/af[]/bfr[] — without it the
// compiler leaves acc in scratch (R1: VGPR_Count=28, 6 GB spill writes).
// ---------------------------------------------------------------------------
__global__ __launch_bounds__(256) void gemm_bt(
    const unsigned short* __restrict__ A, const unsigned short* __restrict__ B,
    const float* __restrict__ bias, int Kp, int N,
    float* __restrict__ outF, int ldF, int nF,
    unsigned short* __restrict__ outB, int ldB, int nB, int relu)
{
    __shared__ __align__(16) unsigned short As[128 * 32];
    __shared__ __align__(16) unsigned short Bs[128 * 32];
    int tid = threadIdx.x;
    int w = tid >> 6, lane = tid & 63;
    int r = lane & 15, q = lane >> 4;
    int m0 = blockIdx.x * 128;
    int n0 = blockIdx.y * 128;
    int wm = (w >> 1) * 64, wn = (w & 1) * 64;
    f32x4 acc[4][4] = {};
    int ktiles = Kp >> 5;

    for (int kt = 0; kt < ktiles; ++kt) {
        int k0 = kt * 32;
#pragma unroll
        for (int iss = 0; iss < 2; ++iss) {
            int chunk = iss * 256 + w * 64 + lane;       // 0..511
            int mm = chunk >> 2, kc = chunk & 3;
            const unsigned short* ga = A + (size_t)(m0 + mm) * Kp + k0 + kc * 8;
            async16(ga, &As[(size_t)(iss * 256 + w * 64) * 8]);
            const unsigned short* gb = B + (size_t)(n0 + mm) * Kp + k0 + kc * 8;
            async16(gb, &Bs[(size_t)(iss * 256 + w * 64) * 8]);
        }
        __syncthreads();
        v8bf16 af[4], bfr[4];
#pragma unroll
        for (int im = 0; im < 4; ++im)
            af[im] = *(const v8bf16*)&As[(wm + im * 16 + r) * 32 + q * 8];
#pragma unroll
        for (int in = 0; in < 4; ++in)
            bfr[in] = *(const v8bf16*)&Bs[(wn + in * 16 + r) * 32 + q * 8];
#pragma unroll
        for (int im = 0; im < 4; ++im)
#pragma unroll
            for (int in = 0; in < 4; ++in)
                acc[im][in] = __builtin_amdgcn_mfma_f32_16x16x32_bf16(
                    af[im], bfr[in], acc[im][in], 0, 0, 0);
        __syncthreads();
    }

#pragma unroll
    for (int im = 0; im < 4; ++im) {
        int rowb = m0 + wm + im * 16 + q * 4;
#pragma unroll
        for (int in = 0; in < 4; ++in) {
            int col = n0 + wn + in * 16 + r;
            float bv = (col < N) ? bias[col] : 0.f;
#pragma unroll
            for (int reg = 0; reg < 4; ++reg) {
                float v = acc[im][in][reg];
                if (col < N) { v += bv; if (relu) v = fmaxf(v, 0.f); }
                else v = 0.f;
                int rr = rowb + reg;
                if (outF && col < nF) outF[(size_t)rr * ldF + col] = v;
                if (outB && col < nB) outB[(size_t)rr * ldB + col] = f2b(v);
            }
        }
    }
}

// ---------------------------------------------------------------------------
// Attention per b: S=QK^T via MFMA, softmax w/ mask, pbar = mean_i P,
// mean_ctx[d] = sum_j pbar[j] * V[j,d]  (mean over queries folded into pbar).
// ---------------------------------------------------------------------------
static __device__ __forceinline__ v8bf16 load_frag(
    const unsigned short* row, int colbase, int d0)
{
    union { unsigned u[4]; v8bf16 v; unsigned short s[8]; } U;
    if (d0 + 8 <= DHH) {
        const unsigned* p = (const unsigned*)(row + colbase + d0);
        U.u[0] = p[0]; U.u[1] = p[1]; U.u[2] = p[2]; U.u[3] = p[3];
    } else {
#pragma unroll
        for (int t = 0; t < 8; ++t)
            U.s[t] = (d0 + t < DHH) ? row[colbase + d0 + t] : (unsigned short)0;
    }
    return U.v;
}

__global__ __launch_bounds__(256) void attn_kernel(
    const unsigned short* __restrict__ qkv,  // chunk rows x LDQ
    const int* __restrict__ hist_nids,
    unsigned short* __restrict__ mean_ctx,   // BSZ x KP bf16
    int c0)
{
    __shared__ float Sp[2][2][LH][LH];
    __shared__ float P[2][LH][LH];
    __shared__ float pbar[2][LH];
    __shared__ int maskv[LH];
    int b = c0 + blockIdx.x;
    int tid = threadIdx.x;
    int lane = tid & 63, w = tid >> 6;
    int r = lane & 15, q = lane >> 4;
    if (tid < LH) maskv[tid] = (hist_nids[b * LH + tid] == 0 && tid != LH - 1) ? 1 : 0;

    const unsigned short* base = qkv + (size_t)blockIdx.x * LH * LDQ;
    int h = w & 1, kh = w >> 1;
    int qoff = h * DHH;
    int koff = DD + h * DHH;
    f32x4 sacc[2][2] = {};
#pragma unroll
    for (int step = 0; step < 7; ++step) {
        int k0 = kh * 224 + step * 32;
        v8bf16 qf[2], kf[2];
#pragma unroll
        for (int im = 0; im < 2; ++im) {
            int mm = im * 16 + r; if (mm >= LH) mm = LH - 1;
            const unsigned short* rp = base + (size_t)mm * LDQ;
            qf[im] = load_frag(rp, qoff, k0 + q * 8);
            kf[im] = load_frag(rp, koff, k0 + q * 8);
        }
#pragma unroll
        for (int im = 0; im < 2; ++im)
#pragma unroll
            for (int in = 0; in < 2; ++in)
                sacc[im][in] = __builtin_amdgcn_mfma_f32_16x16x32_bf16(
                    qf[im], kf[in], sacc[im][in], 0, 0, 0);
    }
#pragma unroll
    for (int im = 0; im < 2; ++im)
#pragma unroll
        for (int in = 0; in < 2; ++in)
#pragma unroll
            for (int reg = 0; reg < 4; ++reg) {
                int i = im * 16 + q * 4 + reg, jj = in * 16 + r;
                if (i < LH && jj < LH) Sp[h][kh][i][jj] = sacc[im][in][reg];
            }
    __syncthreads();

    if (tid < 2 * LH) {
        int hh = tid / LH, i = tid - (tid / LH) * LH;
        const float scale = 0.0482242822f;  // 1/sqrt(430)
        float s[LH], mx = -1e30f;
#pragma unroll
        for (int jj = 0; jj < LH; ++jj) {
            float v = (Sp[hh][0][i][jj] + Sp[hh][1][i][jj]) * scale;
            if (maskv[jj]) v = -1e30f;
            s[jj] = v; mx = fmaxf(mx, v);
        }
        float sum = 0.f;
#pragma unroll
        for (int jj = 0; jj < LH; ++jj) { float e = expf(s[jj] - mx); s[jj] = e; sum += e; }
        float inv = 1.f / sum;
#pragma unroll
        for (int jj = 0; jj < LH; ++jj) P[hh][i][jj] = s[jj] * inv;
    }
    __syncthreads();
    if (tid < 2 * LH) {
        int hh = tid / LH, jj = tid - (tid / LH) * LH;
        float a = 0.f;
#pragma unroll
        for (int i = 0; i < LH; ++i) a += P[hh][i][jj];
        pbar[hh][jj] = a * (1.f / LH);
    }
    __syncthreads();

    for (int d = tid; d < KP; d += 256) {
        float a = 0.f;
        if (d < DD) {
            int hh = d < DHH ? 0 : 1;
            int dd = d - hh * DHH;
            int voff = 2 * DD + hh * DHH + dd;
#pragma unroll
            for (int jj = 0; jj < LH; ++jj)
                a += pbar[hh][jj] * b2f(base[(size_t)jj * LDQ + voff]);
        }
        mean_ctx[(size_t)b * KP + d] = f2b(a);
    }
}

// ---------------------------------------------------------------------------
extern "C" void kernel_launch(void* const* d_in, const int* in_sizes, int n_in,
                              void* d_out, int out_size, void* d_ws, size_t ws_size,
                              hipStream_t stream)
{
    const int*   nids      = (const int*)d_in[0];
    const int*   hist_nids = (const int*)d_in[1];
    const int*   aids      = (const int*)d_in[2];
    const int*   eids      = (const int*)d_in[3];
    const float* hist_ts   = (const float*)d_in[4];
    const int*   dirs      = (const int*)d_in[5];
    const float* node_emb  = (const float*)d_in[6];
    const float* edge_emb  = (const float*)d_in[7];
    const float* anony_emb = (const float*)d_in[8];
    const float* time_w    = (const float*)d_in[9];
    const float* time_b    = (const float*)d_in[10];
    const float* in_proj_w = (const float*)d_in[11];
    const float* in_proj_b = (const float*)d_in[12];
    const float* out_proj_w= (const float*)d_in[13];
    const float* out_proj_b= (const float*)d_in[14];
    const float* outfn_w   = (const float*)d_in[15];
    const float* outfn_b   = (const float*)d_in[16];
    const float* fc1_w     = (const float*)d_in[17];
    const float* fc1_b     = (const float*)d_in[18];
    const float* fc2_w     = (const float*)d_in[19];
    const float* fc2_b     = (const float*)d_in[20];

    float* out_left  = (float*)d_out;
    float* out_right = out_left + (size_t)BSZ * NFD;
    float* out_ts    = out_right + (size_t)BSZ * NFD;

    char* p = (char*)d_ws;
    auto alloc = [&](size_t bytes) -> char* {
        char* r = p; p += (bytes + 255) & ~(size_t)255; return r;
    };
    unsigned short* Wqkv = (unsigned short*)alloc((size_t)LDQ * KP * 2);
    unsigned short* Wop  = (unsigned short*)alloc((size_t)896 * KP * 2);
    unsigned short* Wofn = (unsigned short*)alloc((size_t)256 * 896 * 2);
    unsigned short* Wfc1 = (unsigned short*)alloc((size_t)256 * KP * 2);
    unsigned short* Wfc2 = (unsigned short*)alloc((size_t)256 * 192 * 2);
    unsigned short* meanctx = (unsigned short*)alloc((size_t)BSZ * KP * 2);
    unsigned short* xbuf    = (unsigned short*)alloc((size_t)BSZ * KP * 2);
    unsigned short* tmp1    = (unsigned short*)alloc((size_t)BSZ * 896 * 2);
    unsigned short* hbuf    = (unsigned short*)alloc((size_t)BSZ * 192 * 2);
    size_t fixed = (size_t)(p - (char*)d_ws);

    int CB = 1024;  // chunk of batch; qkv chunk ~110MB stays L3-resident
    while (CB > 128) {
        size_t need = fixed + (size_t)CB * LH * KP * 2 + (size_t)CB * LH * LDQ * 2 + 4096;
        if (need <= ws_size) break;
        CB >>= 1;
    }
    unsigned short* fullc = (unsigned short*)alloc((size_t)CB * LH * KP * 2);
    unsigned short* qkvc  = (unsigned short*)alloc((size_t)CB * LH * LDQ * 2);

    auto conv = [&](const float* s, unsigned short* d, int N_, int K_, int Np_, int Kp_) {
        int total = Np_ * Kp_;
        int blocks = (total + 255) / 256; if (blocks > 4096) blocks = 4096;
        pad_convert<<<dim3(blocks), dim3(256), 0, stream>>>(s, d, N_, K_, Np_, Kp_);
    };
    conv(in_proj_w,  Wqkv, NQKV, DD, LDQ, KP);
    conv(out_proj_w, Wop,  DD,   DD, 896, KP);
    conv(outfn_w,    Wofn, NFD,  DD, 256, 896);
    conv(fc1_w,      Wfc1, NFD,  DD, 256, KP);
    conv(fc2_w,      Wfc2, NFD,  NFD, 256, 192);

    for (int c0 = 0; c0 < BSZ; c0 += CB) {
        build_kernel<<<dim3(CB * LH), dim3(256), 0, stream>>>(
            nids, hist_nids, aids, eids, hist_ts, dirs,
            node_emb, edge_emb, anony_emb, time_w, time_b,
            fullc, xbuf, out_ts, c0);
        gemm_bt<<<dim3(CB * LH / 128, LDQ / 128), dim3(256), 0, stream>>>(
            fullc, Wqkv, in_proj_b, KP, NQKV,
            (float*)nullptr, 0, 0, qkvc, LDQ, LDQ, 0);
        attn_kernel<<<dim3(CB), dim3(256), 0, stream>>>(qkvc, hist_nids, meanctx, c0);
    }
    // E1: tmp1 = relu(mean_ctx @ Wop^T + b)   (mean folded through out_proj)
    gemm_bt<<<dim3(BSZ / 128, 7), dim3(256), 0, stream>>>(
        meanctx, Wop, out_proj_b, KP, DD,
        (float*)nullptr, 0, 0, tmp1, 896, 896, 1);
    // E2: h_prev_left = tmp1 @ Wofn^T + b  -> d_out (fp32) and x cols 0..171 (bf16)
    gemm_bt<<<dim3(BSZ / 128, 2), dim3(256), 0, stream>>>(
        tmp1, Wofn, outfn_b, 896, NFD,
        out_left, NFD, NFD, xbuf, KP, NFD, 0);
    // E3: h = relu(x @ Wfc1^T + b) -> bf16 (zero-padded to 192)
    gemm_bt<<<dim3(BSZ / 128, 2), dim3(256), 0, stream>>>(
        xbuf, Wfc1, fc1_b, KP, NFD,
        (float*)nullptr, 0, 0, hbuf, 192, 192, 1);
    // E4: h_prev_right = h @ Wfc2^T + b -> d_out
    gemm_bt<<<dim3(BSZ / 128, 2), dim3(256), 0, stream>>>(
        hbuf, Wfc2, fc2_b, 192, NFD,
        out_right, NFD, NFD, (unsigned short*)nullptr, 0, 0, 0);
}